// Round 6
// baseline (458.236 us; speedup 1.0000x reference)
//
#include <hip/hip_runtime.h>
#include <math.h>

// Dims: B=4 (b*n), L=1024 (h*w), D_MODEL=256, D_INNER=512, D_STATE=16, DT_RANK=16
// Streams: s=0 forward layer (2*it), s=1 backward layer (2*it+1), natural time order.
// GEMMs: bf16 MFMA 16x16x32, operands in fragment layout [R/16][K/8][16][8].
// Intermediates x, z, xc, y all bf16. dt fp32 (precision: feeds exp chains).
// Scan: chunked 2-pass, 64 chunks x 16 steps, thread-per-d with 16 states in registers.

__device__ __forceinline__ float sigmoidf_(float x){ return 1.f/(1.f+__expf(-x)); }
__device__ __forceinline__ short bf16_(float x){
  unsigned u = __float_as_uint(x);
  u += 0x7FFFu + ((u>>16)&1u);
  return (short)(u>>16);
}
__device__ __forceinline__ float f32_(short s){
  return __uint_as_float(((unsigned)(unsigned short)s)<<16);
}

using fragAB = __attribute__((ext_vector_type(8))) short;   // 8 bf16
using fragC  = __attribute__((ext_vector_type(4))) float;   // 4 f32

// hs[b,l,c] = x[b,c,l]
__global__ __launch_bounds__(256) void k_transpose_in(const float* __restrict__ x, float* __restrict__ hs){
  __shared__ float tile[32][33];
  int b = blockIdx.z;
  int l0 = blockIdx.x*32, c0 = blockIdx.y*32;
  int tx = threadIdx.x, ty = threadIdx.y;
  #pragma unroll
  for (int j=0;j<32;j+=8)
    tile[ty+j][tx] = x[(size_t)b*262144 + (size_t)(c0+ty+j)*1024 + l0 + tx];
  __syncthreads();
  #pragma unroll
  for (int j=0;j<32;j+=8)
    hs[(size_t)b*262144 + (size_t)(l0+ty+j)*256 + (c0+tx)] = tile[tx][ty+j];
}

// out[b,c,l] = 2*racc[b,l,c] + hs[b,l,c]
__global__ __launch_bounds__(256) void k_final(const float* __restrict__ racc, const float* __restrict__ hs, float* __restrict__ out){
  __shared__ float tile[32][33];
  int b = blockIdx.z;
  int l0 = blockIdx.x*32, c0 = blockIdx.y*32;
  int tx = threadIdx.x, ty = threadIdx.y;
  #pragma unroll
  for (int j=0;j<32;j+=8){
    size_t idx = (size_t)b*262144 + (size_t)(l0+ty+j)*256 + c0+tx;
    tile[ty+j][tx] = 2.f*racc[idx] + hs[idx];
  }
  __syncthreads();
  #pragma unroll
  for (int j=0;j<32;j+=8)
    out[(size_t)b*262144 + (size_t)(c0+ty+j)*1024 + l0+tx] = tile[tx][ty+j];
}

// r = hs (+ 2*racc on iter1); racc = r; hn_frag[s] = bf16frag(LN(r)*nw+nb) for s=0,1
__global__ __launch_bounds__(256) void k_ln(const float* __restrict__ hs, float* __restrict__ racc, short* __restrict__ hn_f,
  const float* __restrict__ nw, const float* __restrict__ nb, int layer0, int first){
  int row = blockIdx.x, c = threadIdx.x;
  size_t idx = (size_t)row*256 + c;
  float r = hs[idx];
  if (!first) r += 2.f*racc[idx];
  racc[idx] = r;
  float s1=r, s2=r*r;
  #pragma unroll
  for (int o=32;o>=1;o>>=1){ s1+=__shfl_xor(s1,o); s2+=__shfl_xor(s2,o); }
  __shared__ float red[8];
  int wid=c>>6, lane=c&63;
  if (lane==0){ red[wid]=s1; red[4+wid]=s2; }
  __syncthreads();
  s1 = red[0]+red[1]+red[2]+red[3];
  s2 = red[4]+red[5]+red[6]+red[7];
  float mu = s1*(1.f/256.f);
  float var = s2*(1.f/256.f) - mu*mu;
  float inv = rsqrtf(var + 1e-5f);
  float nv = (r-mu)*inv;
  size_t fo = (((size_t)(row>>4)*32 + (c>>3))*16 + (row&15))*8 + (c&7);
  hn_f[fo]           = bf16_(nv*nw[layer0*256+c] + nb[layer0*256+c]);
  hn_f[1048576 + fo] = bf16_(nv*nw[(layer0+1)*256+c] + nb[(layer0+1)*256+c]);
}

// Convert weights fp32 -> bf16 fragment layout; which==4 zeroes dt_frag K-pad (ktiles 2,3).
__global__ __launch_bounds__(256) void k_wconv(
  const float* __restrict__ inw, const float* __restrict__ xpw,
  const float* __restrict__ dtw, const float* __restrict__ otw,
  short* __restrict__ f_inw, short* __restrict__ f_xpw,
  short* __restrict__ f_dtw, short* __restrict__ f_otw,
  short* __restrict__ dt_f)
{
  int which = blockIdx.y, layer = blockIdx.z;
  int idx = blockIdx.x*256 + threadIdx.x;
  if (which==4){
    if (layer) return;
    if (idx >= 131072) return;            // 2 streams x 256 mtiles x 2 pad-ktiles x 128
    int st = idx >> 16, rem = idx & 65535;
    int mt = rem >> 8, kt2 = (rem>>7)&1, e = rem&127;
    dt_f[(size_t)st*131072 + ((size_t)(mt*4 + 2 + kt2))*128 + e] = 0;
    return;
  }
  const float* src; short* dst; int R,K,Kp;
  if (which==0){ src=inw; dst=f_inw; R=1024; K=256; Kp=256; }
  else if (which==1){ src=xpw; dst=f_xpw; R=48; K=512; Kp=512; }
  else if (which==2){ src=dtw; dst=f_dtw; R=512; K=16; Kp=32; }
  else { src=otw; dst=f_otw; R=256; K=512; Kp=512; }
  int per = (R>>4)*(Kp>>3)*128;
  if (idx >= per) return;
  int e = idx & 127, tile = idx >> 7;
  int nkt = Kp>>3;
  int kt = tile % nkt, rt = tile / nkt;
  int r = rt*16 + (e>>3), k = kt*8 + (e&7);
  float v = (k<K) ? src[((size_t)layer*R + r)*K + k] : 0.f;
  dst[(size_t)layer*per + idx] = bf16_(v);
}

// bf16 MFMA GEMM: C[M,N] = A @ W^T (+second stream if A2), epilogue by mode.
// A,W in frag layout [R/16][K/8][16][8]. Block 128x64, 4 waves, 64x32 per wave.
// mode 0: fp32 C store.  mode 1: fp32 C + bf16 dt-frag of cols<16 into aux1.
// mode 2: softplus(v+bias) fp32 C.  mode 3: no C; col<512 -> bf16 aux1 (x), col>=512 -> bf16 aux2 (z), row-major.
__global__ __launch_bounds__(256) void k_mm(
  const short* __restrict__ Af, long sA,
  const short* __restrict__ Wf, long sW,
  const short* __restrict__ A2f, const short* __restrict__ W2f,
  float* __restrict__ Cb, long sC,
  const float* __restrict__ biasb, long sBias,
  int M, int N, int K, int ldc, int mode,
  short* __restrict__ aux1, long sAux1,
  short* __restrict__ aux2, long sAux2)
{
  int z = blockIdx.z;
  int tid = threadIdx.x;
  int lane = tid & 63, wid = tid >> 6;
  int wm = wid & 1, wn = wid >> 1;
  int K8 = K >> 3;
  int mt_base = blockIdx.y*8 + wm*4;
  int nt_base = blockIdx.x*4 + wn*2;
  int ncap = (N + 15) >> 4;
  const int loff = lane*8;
  fragC acc[4][2] = {};
  const short* Aps[2] = { Af + (size_t)z*sA, A2f };
  const short* Wps[2] = { Wf + (size_t)z*sW, W2f };
  int nseg = A2f ? 2 : 1;
  for (int sgi=0; sgi<nseg; ++sgi){
    const short* A = Aps[sgi];
    const short* W = Wps[sgi];
    for (int kt=0; kt<K8; kt+=4){
      fragAB a[4], b[2];
      #pragma unroll
      for (int i=0;i<4;++i)
        a[i] = *(const fragAB*)(A + ((size_t)(mt_base+i)*K8 + kt)*128 + loff);
      #pragma unroll
      for (int j=0;j<2;++j){
        int nt = nt_base + j; if (nt >= ncap) nt = ncap-1;
        b[j] = *(const fragAB*)(W + ((size_t)nt*K8 + kt)*128 + loff);
      }
      #pragma unroll
      for (int i=0;i<4;++i)
        #pragma unroll
        for (int j=0;j<2;++j)
          acc[i][j] = __builtin_amdgcn_mfma_f32_16x16x32_bf16(a[i], b[j], acc[i][j], 0,0,0);
    }
  }
  float* C = Cb ? Cb + (size_t)z*sC : nullptr;
  const float* bias = biasb ? biasb + (size_t)z*sBias : nullptr;
  int r0 = (lane>>4)*4;
  int cc = lane & 15;
  #pragma unroll
  for (int i=0;i<4;++i){
    int row = (mt_base+i)*16 + r0;
    #pragma unroll
    for (int j=0;j<2;++j){
      int col = (nt_base+j)*16 + cc;
      if (col < N){
        #pragma unroll
        for (int r=0;r<4;++r){
          float v = acc[i][j][r];
          if (bias) v += bias[col];
          if (mode==2){ v = (v > 20.f) ? v : log1pf(__expf(v)); }
          int rr = row + r;
          if (mode==3){
            if (col < 512) aux1[(size_t)z*sAux1 + (size_t)rr*512 + col] = bf16_(v);
            else           aux2[(size_t)z*sAux2 + (size_t)rr*512 + (col-512)] = bf16_(v);
          } else {
            C[(size_t)rr*ldc + col] = v;
            if (mode==1 && col < 16)
              aux1[(size_t)z*sAux1 + (((size_t)(rr>>4)*4 + (col>>3))*16 + (rr&15))*8 + (col&7)] = bf16_(v);
          }
        }
      }
    }
  }
}

// causal (s=0) / anticausal (s=1) depthwise conv over t + SiLU; x bf16 row-major in, xc bf16 frag out.
__global__ __launch_bounds__(256) void k_conv(const short* __restrict__ xb, short* __restrict__ xc_f,
  const float* __restrict__ cw, const float* __restrict__ cb, int layer0){
  int idx = blockIdx.x*256 + threadIdx.x;   // (sb, t, d), d fastest
  int d = idx & 511;
  int t = (idx >> 9) & 1023;
  int sb = idx >> 19;                        // s*4 + b
  int s = sb >> 2, b = sb & 3;
  int layer = layer0 + s;
  const float* w = cw + ((size_t)layer*512 + d)*4;
  float accv = cb[(size_t)layer*512 + d];
  const short* xp = xb + (size_t)s*2097152 + (size_t)b*1024*512 + d;  // row stride 512
  if (s==0){
    #pragma unroll
    for (int k=0;k<4;++k){ int tt = t + k - 3; if (tt>=0) accv = fmaf(f32_(xp[(size_t)tt*512]), w[k], accv); }
  } else {
    #pragma unroll
    for (int k=0;k<4;++k){ int tt = t + 3 - k; if (tt<1024) accv = fmaf(f32_(xp[(size_t)tt*512]), w[k], accv); }
  }
  float v = accv * sigmoidf_(accv);
  int row = b*1024 + t;
  xc_f[(size_t)s*2097152 + (((size_t)(row>>4)*64 + (d>>3))*16 + (row&15))*8 + (d&7)] = bf16_(v);
}

// ---- chunked scan: 64 chunks x 16 steps, thread per (sb,chunk,d), h[16] in registers ----
#define NCHUNK 64
#define CSTEPS 16

__device__ __forceinline__ float ld_xc(const short* xcf, int row, int d){
  return f32_(xcf[(((size_t)(row>>4)*64 + (d>>3))*16 + (row&15))*8 + (d&7)]);
}

__global__ __launch_bounds__(256) void k_scan_a(
  const float* __restrict__ dtv, const short* __restrict__ xc_f,
  const float* __restrict__ dbl, const float* __restrict__ A_log,
  float* __restrict__ dtsum, float* __restrict__ hF, int layer0)
{
  int d = blockIdx.x*256 + threadIdx.x;
  int k = blockIdx.y;
  int sb = blockIdx.z;
  int s = sb >> 2, b = sb & 3;
  int layer = layer0 + s;
  float Av[16];
  #pragma unroll
  for (int n=0;n<16;++n) Av[n] = -__expf(A_log[((size_t)layer*512 + d)*16 + n]);
  const float* dt_p = dtv + (size_t)sb*524288 + d;
  const short* xcf = xc_f + (size_t)s*2097152;
  const float* bc_p = dbl + (size_t)sb*49152;
  float h[16];
  #pragma unroll
  for (int n=0;n<16;++n) h[n] = 0.f;
  float ssum = 0.f;
  int u0 = k*CSTEPS;
  #pragma unroll
  for (int i=0;i<CSTEPS;++i){
    int u = u0 + i;
    int t = s ? (1023 - u) : u;
    int row = b*1024 + t;
    float dtval = dt_p[(size_t)t*512];
    float xv = ld_xc(xcf, row, d);
    const float4* bp = (const float4*)(bc_p + (size_t)t*48 + 16);
    float4 B0 = bp[0], B1 = bp[1], B2 = bp[2], B3 = bp[3];
    float Bv[16] = {B0.x,B0.y,B0.z,B0.w,B1.x,B1.y,B1.z,B1.w,
                    B2.x,B2.y,B2.z,B2.w,B3.x,B3.y,B3.z,B3.w};
    float w = dtval * xv;
    ssum += dtval;
    #pragma unroll
    for (int n=0;n<16;++n)
      h[n] = fmaf(__expf(dtval*Av[n]), h[n], w*Bv[n]);
  }
  size_t base = (size_t)(sb*NCHUNK + k)*512 + d;
  dtsum[base] = ssum;
  float4* hp = (float4*)(hF + base*16);
  #pragma unroll
  for (int q=0;q<4;++q) hp[q] = make_float4(h[4*q],h[4*q+1],h[4*q+2],h[4*q+3]);
}

__global__ __launch_bounds__(256) void k_scan_c(
  const float* __restrict__ dtsum, float* __restrict__ hF,
  const float* __restrict__ A_log, int layer0)
{
  int gid = blockIdx.x*256 + threadIdx.x;  // sb*8192 + d*16 + n
  int sb = gid >> 13;
  int d = (gid >> 4) & 511;
  int n = gid & 15;
  int layer = layer0 + (sb >> 2);
  float Av = -__expf(A_log[((size_t)layer*512 + d)*16 + n]);
  float hrun = 0.f;
  #pragma unroll 8
  for (int k=0;k<NCHUNK;++k){
    size_t base = (size_t)(sb*NCHUNK + k)*512 + d;
    float a = __expf(Av * dtsum[base]);
    float hf = hF[base*16 + n];
    hF[base*16 + n] = hrun;      // h0 for chunk k
    hrun = fmaf(a, hrun, hf);
  }
}

// Pass B: recompute within chunk from h0, emit gated y as bf16 fragments (for out_proj).
__global__ __launch_bounds__(256) void k_scan_b(
  const float* __restrict__ dtv, const short* __restrict__ xc_f, const short* __restrict__ zb,
  const float* __restrict__ dbl, const float* __restrict__ A_log, const float* __restrict__ Dp,
  const float* __restrict__ h0p, short* __restrict__ y_f, int layer0)
{
  int d = blockIdx.x*256 + threadIdx.x;
  int k = blockIdx.y;
  int sb = blockIdx.z;
  int s = sb >> 2, b = sb & 3;
  int layer = layer0 + s;
  float Av[16];
  #pragma unroll
  for (int n=0;n<16;++n) Av[n] = -__expf(A_log[((size_t)layer*512 + d)*16 + n]);
  float Dv = Dp[(size_t)layer*512 + d];
  const float* dt_p = dtv + (size_t)sb*524288 + d;
  const short* xcf = xc_f + (size_t)s*2097152;
  const short* z_p = zb + (size_t)s*2097152 + (size_t)b*1024*512 + d;
  const float* bc_p = dbl + (size_t)sb*49152;
  size_t base = (size_t)(sb*NCHUNK + k)*512 + d;
  float h[16];
  const float4* hp = (const float4*)(h0p + base*16);
  #pragma unroll
  for (int q=0;q<4;++q){
    float4 v = hp[q];
    h[4*q]=v.x; h[4*q+1]=v.y; h[4*q+2]=v.z; h[4*q+3]=v.w;
  }
  short* yo = y_f + (size_t)s*2097152;
  int u0 = k*CSTEPS;
  #pragma unroll
  for (int i=0;i<CSTEPS;++i){
    int u = u0 + i;
    int t = s ? (1023 - u) : u;
    int row = b*1024 + t;
    float dtval = dt_p[(size_t)t*512];
    float xv = ld_xc(xcf, row, d);
    const float4* bp = (const float4*)(bc_p + (size_t)t*48 + 16);
    float4 B0 = bp[0], B1 = bp[1], B2 = bp[2], B3 = bp[3];
    float4 C0 = bp[4], C1 = bp[5], C2 = bp[6], C3 = bp[7];
    float Bv[16] = {B0.x,B0.y,B0.z,B0.w,B1.x,B1.y,B1.z,B1.w,
                    B2.x,B2.y,B2.z,B2.w,B3.x,B3.y,B3.z,B3.w};
    float Cv[16] = {C0.x,C0.y,C0.z,C0.w,C1.x,C1.y,C1.z,C1.w,
                    C2.x,C2.y,C2.z,C2.w,C3.x,C3.y,C3.z,C3.w};
    float w = dtval * xv;
    float y = 0.f;
    #pragma unroll
    for (int n=0;n<16;++n){
      h[n] = fmaf(__expf(dtval*Av[n]), h[n], w*Bv[n]);
      y = fmaf(h[n], Cv[n], y);
    }
    float zv = f32_(z_p[(size_t)t*512]);
    float yv = (y + Dv*xv) * (zv*sigmoidf_(zv));
    yo[(((size_t)(row>>4)*64 + (d>>3))*16 + (row&15))*8 + (d&7)] = bf16_(yv);
  }
}

extern "C" void kernel_launch(void* const* d_in, const int* in_sizes, int n_in,
                              void* d_out, int out_size, void* d_ws, size_t ws_size,
                              hipStream_t stream) {
  const float* x        = (const float*)d_in[0];
  const float* norm_w   = (const float*)d_in[1];
  const float* norm_b   = (const float*)d_in[2];
  const float* in_w     = (const float*)d_in[3];
  const float* conv_w   = (const float*)d_in[4];
  const float* conv_b   = (const float*)d_in[5];
  const float* xproj_w  = (const float*)d_in[6];
  const float* dtproj_w = (const float*)d_in[7];
  const float* dtproj_b = (const float*)d_in[8];
  const float* A_log    = (const float*)d_in[9];
  const float* Dp       = (const float*)d_in[10];
  const float* out_w    = (const float*)d_in[11];
  float* out = (float*)d_out;
  float* ws = (float*)d_ws;

  float* hs    = ws;                        // 1048576 f
  float* racc  = ws + 1048576;              // 1048576 f
  short* hn_f  = (short*)(ws + 2097152);    // 2x1048576 bf16
  short* xb    = (short*)(ws + 3145728);    // 2x2097152 bf16 (x, row-major [s][row][512])
  short* zb    = (short*)(ws + 5242880);    // 2x2097152 bf16 (z, row-major)
  short* xc_f  = (short*)(ws + 7340032);    // 2x2097152 bf16 (frag)
  short* y_f   = (short*)(ws + 9437184);    // 2x2097152 bf16 (frag)
  float* dbl   = ws + 11534336;             // 393216 f
  float* dtv   = ws + 12058624;             // 4194304 f
  short* dt_f  = (short*)(ws + 16252928);   // 2x131072 bf16 (K padded to 32)
  float* dtsum = ws + 16384000;             // 8x64x512 = 262144 f
  float* hF    = ws + 16646144;             // 8x64x512x16 = 4194304 f
  short* w_inw = (short*)(ws + 20840448);   // 4x262144 bf16
  short* w_xp  = w_inw + 1048576;           // 4x24576
  short* w_dt  = w_xp + 98304;              // 4x16384
  short* w_out = w_dt + 65536;              // 4x131072

  k_wconv<<<dim3(1024,5,4), 256, 0, stream>>>(in_w, xproj_w, dtproj_w, out_w,
      w_inw, w_xp, w_dt, w_out, dt_f);
  k_transpose_in<<<dim3(32,8,4), dim3(32,8), 0, stream>>>(x, hs);

  for (int it=0; it<2; ++it){
    int layer0 = 2*it;
    k_ln<<<4096, 256, 0, stream>>>(hs, racc, hn_f, norm_w, norm_b, layer0, it==0 ? 1 : 0);
    // in_proj: x,z[s] = hn[s] @ in_w[layer0+s]^T  (M=4096, N=1024, K=256) -> bf16 x/z
    k_mm<<<dim3(16,32,2), 256, 0, stream>>>(hn_f, 1048576L, w_inw + (size_t)layer0*262144, 262144L,
        nullptr, nullptr, nullptr, 0L, nullptr, 0L, 4096, 1024, 256, 0, 3,
        xb, 2097152L, zb, 2097152L);
    k_conv<<<16384, 256, 0, stream>>>(xb, xc_f, conv_w, conv_b, layer0);
    // xproj: dbl[s] = xc[s] @ xproj_w[layer0+s]^T  (M=4096, N=48, K=512) + dt frag epilogue
    k_mm<<<dim3(1,32,2), 256, 0, stream>>>(xc_f, 2097152L, w_xp + (size_t)layer0*24576, 24576L,
        nullptr, nullptr, dbl, 196608L, nullptr, 0L, 4096, 48, 512, 48, 1,
        dt_f, 131072L, nullptr, 0L);
    // dtproj: dtv[s] = softplus(dt[s] @ dtproj_w^T + b)  (M=4096, N=512, K=16 padded to 32)
    k_mm<<<dim3(8,32,2), 256, 0, stream>>>(dt_f, 131072L, w_dt + (size_t)layer0*16384, 16384L,
        nullptr, nullptr, dtv, 2097152L, dtproj_b + (size_t)layer0*512, 512L, 4096, 512, 32, 512, 2,
        nullptr, 0L, nullptr, 0L);
    // chunked scan
    k_scan_a<<<dim3(2,NCHUNK,8), 256, 0, stream>>>(dtv, xc_f, dbl, A_log, dtsum, hF, layer0);
    k_scan_c<<<256, 256, 0, stream>>>(dtsum, hF, A_log, layer0);
    k_scan_b<<<dim3(2,NCHUNK,8), 256, 0, stream>>>(dtv, xc_f, zb, dbl, A_log, Dp, hF, y_f, layer0);
    // out_proj (dual-stream): hs = y_f0 @ out_w[layer0]^T + y_f1 @ out_w[layer0+1]^T
    k_mm<<<dim3(4,32,1), 256, 0, stream>>>(y_f, 0L, w_out + (size_t)layer0*131072, 0L,
        y_f + 2097152, w_out + (size_t)(layer0+1)*131072, hs, 0L, nullptr, 0L,
        4096, 256, 512, 256, 0, nullptr, 0L, nullptr, 0L);
  }
  k_final<<<dim3(32,8,4), dim3(32,8), 0, stream>>>(racc, hs, out);
}

// Round 7
// 446.317 us; speedup vs baseline: 1.0267x; 1.0267x over previous
//
#include <hip/hip_runtime.h>
#include <math.h>

// Dims: B=4 (b*n), L=1024 (h*w), D_MODEL=256, D_INNER=512, D_STATE=16, DT_RANK=16
// Streams: s=0 forward layer (2*it), s=1 backward layer (2*it+1), natural time order.
// GEMMs: bf16 MFMA 16x16x32, frag layout [R/16][K/8][16][8]. x,z,xc,y bf16; dt fp32.
// Scan: chunked 2-pass (64 chunks x 16 steps) + parallel wave-shuffle combine.

__device__ __forceinline__ float sigmoidf_(float x){ return 1.f/(1.f+__expf(-x)); }
__device__ __forceinline__ short bf16_(float x){
  unsigned u = __float_as_uint(x);
  u += 0x7FFFu + ((u>>16)&1u);
  return (short)(u>>16);
}
__device__ __forceinline__ float f32_(short s){
  return __uint_as_float(((unsigned)(unsigned short)s)<<16);
}

using fragAB = __attribute__((ext_vector_type(8))) short;   // 8 bf16 (K=32 slice)
using fragC  = __attribute__((ext_vector_type(4))) float;   // 4 f32

// hs[b,l,c] = x[b,c,l]
__global__ __launch_bounds__(256) void k_transpose_in(const float* __restrict__ x, float* __restrict__ hs){
  __shared__ float tile[32][33];
  int b = blockIdx.z;
  int l0 = blockIdx.x*32, c0 = blockIdx.y*32;
  int tx = threadIdx.x, ty = threadIdx.y;
  #pragma unroll
  for (int j=0;j<32;j+=8)
    tile[ty+j][tx] = x[(size_t)b*262144 + (size_t)(c0+ty+j)*1024 + l0 + tx];
  __syncthreads();
  #pragma unroll
  for (int j=0;j<32;j+=8)
    hs[(size_t)b*262144 + (size_t)(l0+ty+j)*256 + (c0+tx)] = tile[tx][ty+j];
}

// out[b,c,l] = 2*racc[b,l,c] + hs[b,l,c]
__global__ __launch_bounds__(256) void k_final(const float* __restrict__ racc, const float* __restrict__ hs, float* __restrict__ out){
  __shared__ float tile[32][33];
  int b = blockIdx.z;
  int l0 = blockIdx.x*32, c0 = blockIdx.y*32;
  int tx = threadIdx.x, ty = threadIdx.y;
  #pragma unroll
  for (int j=0;j<32;j+=8){
    size_t idx = (size_t)b*262144 + (size_t)(l0+ty+j)*256 + c0+tx;
    tile[ty+j][tx] = 2.f*racc[idx] + hs[idx];
  }
  __syncthreads();
  #pragma unroll
  for (int j=0;j<32;j+=8)
    out[(size_t)b*262144 + (size_t)(c0+ty+j)*1024 + l0+tx] = tile[tx][ty+j];
}

// r = hs (+ 2*racc on iter1); racc = r; hn_frag[s] = bf16frag(LN(r)*nw+nb) for s=0,1
__global__ __launch_bounds__(256) void k_ln(const float* __restrict__ hs, float* __restrict__ racc, short* __restrict__ hn_f,
  const float* __restrict__ nw, const float* __restrict__ nb, int layer0, int first){
  int row = blockIdx.x, c = threadIdx.x;
  size_t idx = (size_t)row*256 + c;
  float r = hs[idx];
  if (!first) r += 2.f*racc[idx];
  racc[idx] = r;
  float s1=r, s2=r*r;
  #pragma unroll
  for (int o=32;o>=1;o>>=1){ s1+=__shfl_xor(s1,o); s2+=__shfl_xor(s2,o); }
  __shared__ float red[8];
  int wid=c>>6, lane=c&63;
  if (lane==0){ red[wid]=s1; red[4+wid]=s2; }
  __syncthreads();
  s1 = red[0]+red[1]+red[2]+red[3];
  s2 = red[4]+red[5]+red[6]+red[7];
  float mu = s1*(1.f/256.f);
  float var = s2*(1.f/256.f) - mu*mu;
  float inv = rsqrtf(var + 1e-5f);
  float nv = (r-mu)*inv;
  size_t fo = (((size_t)(row>>4)*32 + (c>>3))*16 + (row&15))*8 + (c&7);
  hn_f[fo]           = bf16_(nv*nw[layer0*256+c] + nb[layer0*256+c]);
  hn_f[1048576 + fo] = bf16_(nv*nw[(layer0+1)*256+c] + nb[(layer0+1)*256+c]);
}

// Convert weights fp32 -> bf16 fragment layout. Flat exact-size grid (6784 blocks).
__global__ __launch_bounds__(256) void k_wconv(
  const float* __restrict__ inw, const float* __restrict__ xpw,
  const float* __restrict__ dtw, const float* __restrict__ otw,
  short* __restrict__ f_inw, short* __restrict__ f_xpw,
  short* __restrict__ f_dtw, short* __restrict__ f_otw)
{
  int b = blockIdx.x, tid = threadIdx.x;
  int which, layer, idx;
  if (b < 4096){ which=0; layer=b>>10; idx=((b&1023)<<8)+tid; }
  else if (b < 4480){ int r=b-4096; which=1; layer=r/96;  idx=(r%96)*256+tid; }
  else if (b < 4736){ int r=b-4480; which=2; layer=r>>6;  idx=(r&63)*256+tid; }
  else              { int r=b-4736; which=3; layer=r>>9;  idx=(r&511)*256+tid; }
  const float* src; short* dst; int R,K,Kp;
  if (which==0){ src=inw; dst=f_inw; R=1024; K=256; Kp=256; }
  else if (which==1){ src=xpw; dst=f_xpw; R=48; K=512; Kp=512; }
  else if (which==2){ src=dtw; dst=f_dtw; R=512; K=16; Kp=32; }
  else { src=otw; dst=f_otw; R=256; K=512; Kp=512; }
  int per = (R>>4)*(Kp>>3)*128;
  int e = idx & 127, tile = idx >> 7;
  int nkt = Kp>>3;
  int kt = tile % nkt, rt = tile / nkt;
  int r = rt*16 + (e>>3), k = kt*8 + (e&7);
  float v = (k<K) ? src[((size_t)layer*R + r)*K + k] : 0.f;
  dst[(size_t)layer*per + idx] = bf16_(v);
}

// bf16 MFMA GEMM, 128x128 block, 4 waves, 64x64/wave (4 mtiles x 4 ntiles).
// mode 0: fp32 C store. mode 3: no C; col<512 -> bf16 aux1 (x), col>=512 -> bf16 aux2 (z), row-major 512-wide.
__global__ __launch_bounds__(256) void k_mm4(
  const short* __restrict__ Af, long sA,
  const short* __restrict__ Wf, long sW,
  const short* __restrict__ A2f, const short* __restrict__ W2f,
  float* __restrict__ Cb, long sC,
  int K, int ldc, int mode,
  short* __restrict__ aux1, long sAux1,
  short* __restrict__ aux2, long sAux2)
{
  int z = blockIdx.z;
  int tid = threadIdx.x;
  int lane = tid & 63, wid = tid >> 6;
  int wm = wid & 1, wn = wid >> 1;
  int K8 = K >> 3;
  int mt_base = blockIdx.y*8 + wm*4;
  int nt_base = blockIdx.x*8 + wn*4;
  const int loff = lane*8;
  fragC acc[4][4] = {};
  const short* Aps[2] = { Af + (size_t)z*sA, A2f };
  const short* Wps[2] = { Wf + (size_t)z*sW, W2f };
  int nseg = A2f ? 2 : 1;
  for (int sgi=0; sgi<nseg; ++sgi){
    const short* A = Aps[sgi];
    const short* W = Wps[sgi];
    for (int kt=0; kt<K8; kt+=4){
      fragAB a[4], b[4];
      #pragma unroll
      for (int i=0;i<4;++i)
        a[i] = *(const fragAB*)(A + ((size_t)(mt_base+i)*K8 + kt)*128 + loff);
      #pragma unroll
      for (int j=0;j<4;++j)
        b[j] = *(const fragAB*)(W + ((size_t)(nt_base+j)*K8 + kt)*128 + loff);
      #pragma unroll
      for (int i=0;i<4;++i)
        #pragma unroll
        for (int j=0;j<4;++j)
          acc[i][j] = __builtin_amdgcn_mfma_f32_16x16x32_bf16(a[i], b[j], acc[i][j], 0,0,0);
    }
  }
  float* C = Cb ? Cb + (size_t)z*sC : nullptr;
  int r0 = (lane>>4)*4;
  int cc = lane & 15;
  #pragma unroll
  for (int i=0;i<4;++i){
    int row = (mt_base+i)*16 + r0;
    #pragma unroll
    for (int j=0;j<4;++j){
      int col = (nt_base+j)*16 + cc;
      #pragma unroll
      for (int r=0;r<4;++r){
        float v = acc[i][j][r];
        int rr = row + r;
        if (mode==3){
          if (col < 512) aux1[(size_t)z*sAux1 + (size_t)rr*512 + col] = bf16_(v);
          else           aux2[(size_t)z*sAux2 + (size_t)rr*512 + (col-512)] = bf16_(v);
        } else {
          C[(size_t)rr*ldc + col] = v;
        }
      }
    }
  }
}

// Fused xproj + dtproj. Block = 32 rows, 4 waves. Stage1: 48-col xproj (dt->LDS, B/C->dbl).
// Stage2: dtproj M=32,N=512,K=32(pad) from LDS + softplus -> dtv.
__global__ __launch_bounds__(256) void k_xpdt(
  const short* __restrict__ xc_f, const short* __restrict__ wxp,
  const short* __restrict__ wdt, const float* __restrict__ dtb,
  float* __restrict__ dbl, float* __restrict__ dtv, int layer0)
{
  __shared__ short dt_lds[32][24];
  int z = blockIdx.y;
  int by = blockIdx.x;             // 0..127, 32 rows each
  int layer = layer0 + z;
  int tid = threadIdx.x, lane = tid & 63, wn = tid >> 6;
  const short* A = xc_f + (size_t)z*2097152;
  const short* W = wxp + (size_t)layer*24576;
  int mt0 = by*2;
  const int loff = lane*8;
  int r0 = (lane>>4)*4, cc = lane & 15;
  // stage 1
  {
    fragC acc[2] = {};
    int nt = wn < 3 ? wn : 2;
    for (int kt=0; kt<64; kt+=4){
      fragAB a0 = *(const fragAB*)(A + ((size_t)(mt0+0)*64 + kt)*128 + loff);
      fragAB a1 = *(const fragAB*)(A + ((size_t)(mt0+1)*64 + kt)*128 + loff);
      fragAB b  = *(const fragAB*)(W + ((size_t)nt*64 + kt)*128 + loff);
      acc[0] = __builtin_amdgcn_mfma_f32_16x16x32_bf16(a0, b, acc[0], 0,0,0);
      acc[1] = __builtin_amdgcn_mfma_f32_16x16x32_bf16(a1, b, acc[1], 0,0,0);
    }
    int col = nt*16 + cc;
    #pragma unroll
    for (int i=0;i<2;++i){
      int lr = i*16 + r0;                 // local row base
      int grow = by*32 + lr;
      #pragma unroll
      for (int r=0;r<4;++r){
        float v = acc[i][r];
        if (wn==1 || wn==2)
          dbl[(size_t)z*196608 + (size_t)(grow+r)*48 + col] = v;
        if (wn==0)
          dt_lds[lr+r][cc] = bf16_(v);
      }
    }
  }
  __syncthreads();
  // stage 2
  {
    float* dto = dtv + (size_t)z*2097152;
    const float* bias = dtb + (size_t)layer*512;
    const short* WD = wdt + (size_t)layer*16384;
    int kq = lane >> 4;
    fragAB a2[2];
    #pragma unroll
    for (int i=0;i<2;++i){
      fragAB t = {};
      if (kq < 2){
        #pragma unroll
        for (int j=0;j<8;++j) t[j] = dt_lds[i*16 + (lane&15)][kq*8 + j];
      }
      a2[i] = t;
    }
    #pragma unroll
    for (int c2=0;c2<2;++c2){
      fragC acc2[2][4] = {};
      fragAB b2[4];
      #pragma unroll
      for (int j=0;j<4;++j){
        int ntj = wn*8 + c2*4 + j;
        b2[j] = *(const fragAB*)(WD + ((size_t)ntj*4)*128 + loff);
      }
      #pragma unroll
      for (int i=0;i<2;++i)
        #pragma unroll
        for (int j=0;j<4;++j)
          acc2[i][j] = __builtin_amdgcn_mfma_f32_16x16x32_bf16(a2[i], b2[j], acc2[i][j], 0,0,0);
      #pragma unroll
      for (int i=0;i<2;++i){
        int grow = by*32 + i*16 + r0;
        #pragma unroll
        for (int j=0;j<4;++j){
          int col2 = (wn*8 + c2*4 + j)*16 + cc;
          #pragma unroll
          for (int r=0;r<4;++r){
            float v = acc2[i][j][r] + bias[col2];
            v = (v > 20.f) ? v : log1pf(__expf(v));
            dto[(size_t)(grow+r)*512 + col2] = v;
          }
        }
      }
    }
  }
}

// causal (s=0) / anticausal (s=1) depthwise conv over t + SiLU; x bf16 row-major in, xc bf16 frag out.
__global__ __launch_bounds__(256) void k_conv(const short* __restrict__ xb, short* __restrict__ xc_f,
  const float* __restrict__ cw, const float* __restrict__ cb, int layer0){
  int idx = blockIdx.x*256 + threadIdx.x;   // (sb, t, d), d fastest
  int d = idx & 511;
  int t = (idx >> 9) & 1023;
  int sb = idx >> 19;                        // s*4 + b
  int s = sb >> 2, b = sb & 3;
  int layer = layer0 + s;
  const float* w = cw + ((size_t)layer*512 + d)*4;
  float accv = cb[(size_t)layer*512 + d];
  const short* xp = xb + (size_t)s*2097152 + (size_t)b*1024*512 + d;
  if (s==0){
    #pragma unroll
    for (int k=0;k<4;++k){ int tt = t + k - 3; if (tt>=0) accv = fmaf(f32_(xp[(size_t)tt*512]), w[k], accv); }
  } else {
    #pragma unroll
    for (int k=0;k<4;++k){ int tt = t + 3 - k; if (tt<1024) accv = fmaf(f32_(xp[(size_t)tt*512]), w[k], accv); }
  }
  float v = accv * sigmoidf_(accv);
  int row = b*1024 + t;
  xc_f[(size_t)s*2097152 + (((size_t)(row>>4)*64 + (d>>3))*16 + (row&15))*8 + (d&7)] = bf16_(v);
}

// ---- chunked scan: 64 chunks x 16 steps ----
#define NCHUNK 64
#define CSTEPS 16

__device__ __forceinline__ float ld_xc(const short* xcf, int row, int d){
  return f32_(xcf[(((size_t)(row>>4)*64 + (d>>3))*16 + (row&15))*8 + (d&7)]);
}

__global__ __launch_bounds__(256) void k_scan_a(
  const float* __restrict__ dtv, const short* __restrict__ xc_f,
  const float* __restrict__ dbl, const float* __restrict__ A_log,
  float* __restrict__ dtsum, float* __restrict__ hF, int layer0)
{
  int d = blockIdx.x*256 + threadIdx.x;
  int k = blockIdx.y;
  int sb = blockIdx.z;
  int s = sb >> 2, b = sb & 3;
  int layer = layer0 + s;
  float Av[16];
  #pragma unroll
  for (int n=0;n<16;++n) Av[n] = -__expf(A_log[((size_t)layer*512 + d)*16 + n]);
  const float* dt_p = dtv + (size_t)sb*524288 + d;
  const short* xcf = xc_f + (size_t)s*2097152;
  const float* bc_p = dbl + (size_t)sb*49152;
  float h[16];
  #pragma unroll
  for (int n=0;n<16;++n) h[n] = 0.f;
  float ssum = 0.f;
  int u0 = k*CSTEPS;
  #pragma unroll
  for (int i=0;i<CSTEPS;++i){
    int u = u0 + i;
    int t = s ? (1023 - u) : u;
    int row = b*1024 + t;
    float dtval = dt_p[(size_t)t*512];
    float xv = ld_xc(xcf, row, d);
    const float4* bp = (const float4*)(bc_p + (size_t)t*48 + 16);
    float4 B0 = bp[0], B1 = bp[1], B2 = bp[2], B3 = bp[3];
    float Bv[16] = {B0.x,B0.y,B0.z,B0.w,B1.x,B1.y,B1.z,B1.w,
                    B2.x,B2.y,B2.z,B2.w,B3.x,B3.y,B3.z,B3.w};
    float w = dtval * xv;
    ssum += dtval;
    #pragma unroll
    for (int n=0;n<16;++n)
      h[n] = fmaf(__expf(dtval*Av[n]), h[n], w*Bv[n]);
  }
  size_t base = (size_t)(sb*NCHUNK + k)*512 + d;
  dtsum[base] = ssum;
  float4* hp = (float4*)(hF + base*16);
  #pragma unroll
  for (int q=0;q<4;++q) hp[q] = make_float4(h[4*q],h[4*q+1],h[4*q+2],h[4*q+3]);
}

// Parallel combine: block = (d, sb); wave-shuffle exclusive scan over 64 chunk states, in place.
__global__ __launch_bounds__(256) void k_scan_c(
  const float* __restrict__ dtsum, float* __restrict__ hF,
  const float* __restrict__ A_log, int layer0)
{
  __shared__ float tile[64][17];
  __shared__ float ds[64];
  int d = blockIdx.x, sb = blockIdx.y;
  int tid = threadIdx.x, lane = tid & 63, w = tid >> 6;
  int layer = layer0 + (sb >> 2);
  size_t base = (size_t)sb*64*8192 + (size_t)d*16;    // + k*8192 + n
  {
    int k = tid >> 2, n0 = (tid & 3)*4;
    float4 v = *(const float4*)(hF + base + (size_t)k*8192 + n0);
    tile[k][n0+0]=v.x; tile[k][n0+1]=v.y; tile[k][n0+2]=v.z; tile[k][n0+3]=v.w;
  }
  if (tid < 64) ds[tid] = dtsum[((size_t)sb*64 + tid)*512 + d];
  __syncthreads();
  float dsk = ds[lane];
  #pragma unroll
  for (int p=0;p<4;++p){
    int n = p*4 + w;
    float Av = -__expf(A_log[((size_t)layer*512 + d)*16 + n]);
    float a = __expf(Av * dsk);
    float h = tile[lane][n];
    #pragma unroll
    for (int o=1;o<64;o<<=1){
      float au = __shfl_up(a, o);
      float hu = __shfl_up(h, o);
      if (lane >= o){ h = fmaf(a, hu, h); a *= au; }
    }
    float h0 = __shfl_up(h, 1);
    if (lane == 0) h0 = 0.f;
    tile[lane][n] = h0;
  }
  __syncthreads();
  {
    int k = tid >> 2, n0 = (tid & 3)*4;
    float4 v = make_float4(tile[k][n0], tile[k][n0+1], tile[k][n0+2], tile[k][n0+3]);
    *(float4*)(hF + base + (size_t)k*8192 + n0) = v;
  }
}

// Pass B: recompute within chunk from h0 (now stored in hF), emit gated y as bf16 fragments.
__global__ __launch_bounds__(256) void k_scan_b(
  const float* __restrict__ dtv, const short* __restrict__ xc_f, const short* __restrict__ zb,
  const float* __restrict__ dbl, const float* __restrict__ A_log, const float* __restrict__ Dp,
  const float* __restrict__ h0p, short* __restrict__ y_f, int layer0)
{
  int d = blockIdx.x*256 + threadIdx.x;
  int k = blockIdx.y;
  int sb = blockIdx.z;
  int s = sb >> 2, b = sb & 3;
  int layer = layer0 + s;
  float Av[16];
  #pragma unroll
  for (int n=0;n<16;++n) Av[n] = -__expf(A_log[((size_t)layer*512 + d)*16 + n]);
  float Dv = Dp[(size_t)layer*512 + d];
  const float* dt_p = dtv + (size_t)sb*524288 + d;
  const short* xcf = xc_f + (size_t)s*2097152;
  const short* z_p = zb + (size_t)s*2097152 + (size_t)b*1024*512 + d;
  const float* bc_p = dbl + (size_t)sb*49152;
  size_t base = (size_t)(sb*NCHUNK + k)*512 + d;
  float h[16];
  const float4* hp = (const float4*)(h0p + base*16);
  #pragma unroll
  for (int q=0;q<4;++q){
    float4 v = hp[q];
    h[4*q]=v.x; h[4*q+1]=v.y; h[4*q+2]=v.z; h[4*q+3]=v.w;
  }
  short* yo = y_f + (size_t)s*2097152;
  int u0 = k*CSTEPS;
  #pragma unroll
  for (int i=0;i<CSTEPS;++i){
    int u = u0 + i;
    int t = s ? (1023 - u) : u;
    int row = b*1024 + t;
    float dtval = dt_p[(size_t)t*512];
    float xv = ld_xc(xcf, row, d);
    const float4* bp = (const float4*)(bc_p + (size_t)t*48 + 16);
    float4 B0 = bp[0], B1 = bp[1], B2 = bp[2], B3 = bp[3];
    float4 C0 = bp[4], C1 = bp[5], C2 = bp[6], C3 = bp[7];
    float Bv[16] = {B0.x,B0.y,B0.z,B0.w,B1.x,B1.y,B1.z,B1.w,
                    B2.x,B2.y,B2.z,B2.w,B3.x,B3.y,B3.z,B3.w};
    float Cv[16] = {C0.x,C0.y,C0.z,C0.w,C1.x,C1.y,C1.z,C1.w,
                    C2.x,C2.y,C2.z,C2.w,C3.x,C3.y,C3.z,C3.w};
    float w = dtval * xv;
    float y = 0.f;
    #pragma unroll
    for (int n=0;n<16;++n){
      h[n] = fmaf(__expf(dtval*Av[n]), h[n], w*Bv[n]);
      y = fmaf(h[n], Cv[n], y);
    }
    float zv = f32_(z_p[(size_t)t*512]);
    float yv = (y + Dv*xv) * (zv*sigmoidf_(zv));
    yo[(((size_t)(row>>4)*64 + (d>>3))*16 + (row&15))*8 + (d&7)] = bf16_(yv);
  }
}

extern "C" void kernel_launch(void* const* d_in, const int* in_sizes, int n_in,
                              void* d_out, int out_size, void* d_ws, size_t ws_size,
                              hipStream_t stream) {
  const float* x        = (const float*)d_in[0];
  const float* norm_w   = (const float*)d_in[1];
  const float* norm_b   = (const float*)d_in[2];
  const float* in_w     = (const float*)d_in[3];
  const float* conv_w   = (const float*)d_in[4];
  const float* conv_b   = (const float*)d_in[5];
  const float* xproj_w  = (const float*)d_in[6];
  const float* dtproj_w = (const float*)d_in[7];
  const float* dtproj_b = (const float*)d_in[8];
  const float* A_log    = (const float*)d_in[9];
  const float* Dp       = (const float*)d_in[10];
  const float* out_w    = (const float*)d_in[11];
  float* out = (float*)d_out;
  float* ws = (float*)d_ws;

  float* hs    = ws;                        // 1048576 f
  float* racc  = ws + 1048576;              // 1048576 f
  short* hn_f  = (short*)(ws + 2097152);    // 2x1048576 bf16
  short* xb    = (short*)(ws + 3145728);    // 2x2097152 bf16 (x row-major [s][row][512])
  short* zb    = (short*)(ws + 5242880);    // 2x2097152 bf16 (z row-major)
  short* xc_f  = (short*)(ws + 7340032);    // 2x2097152 bf16 (frag)
  short* y_f   = (short*)(ws + 9437184);    // 2x2097152 bf16 (frag)
  float* dbl   = ws + 11534336;             // 393216 f
  float* dtv   = ws + 12058624;             // 4194304 f
  float* dtsum = ws + 16252928;             // 262144 f
  float* hF    = ws + 16515072;             // 4194304 f (hF, then h0 in place)
  short* w_inw = (short*)(ws + 20709376);   // 4x262144 bf16
  short* w_xp  = w_inw + 1048576;           // 4x24576
  short* w_dt  = w_xp + 98304;              // 4x16384
  short* w_out = w_dt + 65536;              // 4x131072

  k_wconv<<<6784, 256, 0, stream>>>(in_w, xproj_w, dtproj_w, out_w, w_inw, w_xp, w_dt, w_out);
  k_transpose_in<<<dim3(32,8,4), dim3(32,8), 0, stream>>>(x, hs);

  for (int it=0; it<2; ++it){
    int layer0 = 2*it;
    k_ln<<<4096, 256, 0, stream>>>(hs, racc, hn_f, norm_w, norm_b, layer0, it==0 ? 1 : 0);
    // in_proj: x,z[s] = hn[s] @ in_w[layer0+s]^T  (M=4096, N=1024, K=256) -> bf16 x/z
    k_mm4<<<dim3(8,32,2), 256, 0, stream>>>(hn_f, 1048576L, w_inw + (size_t)layer0*262144, 262144L,
        nullptr, nullptr, nullptr, 0L, 256, 0, 3, xb, 2097152L, zb, 2097152L);
    k_conv<<<16384, 256, 0, stream>>>(xb, xc_f, conv_w, conv_b, layer0);
    // fused xproj + dtproj
    k_xpdt<<<dim3(128,2), 256, 0, stream>>>(xc_f, w_xp, w_dt, dtproj_b, dbl, dtv, layer0);
    // chunked scan
    k_scan_a<<<dim3(2,NCHUNK,8), 256, 0, stream>>>(dtv, xc_f, dbl, A_log, dtsum, hF, layer0);
    k_scan_c<<<dim3(512,8), 256, 0, stream>>>(dtsum, hF, A_log, layer0);
    k_scan_b<<<dim3(2,NCHUNK,8), 256, 0, stream>>>(dtv, xc_f, zb, dbl, A_log, Dp, hF, y_f, layer0);
    // out_proj (dual-stream): hs = y_f0 @ out_w[layer0]^T + y_f1 @ out_w[layer0+1]^T
    k_mm4<<<dim3(2,32,1), 256, 0, stream>>>(y_f, 0L, w_out + (size_t)layer0*131072, 0L,
        y_f + 2097152, w_out + (size_t)(layer0+1)*131072, hs, 0L, 512, 256, 0,
        nullptr, 0L, nullptr, 0L);
  }
  k_final<<<dim3(32,8,4), dim3(32,8), 0, stream>>>(racc, hs, out);
}

// Round 11
// 384.528 us; speedup vs baseline: 1.1917x; 1.1607x over previous
//
#include <hip/hip_runtime.h>
#include <math.h>

// Dims: B=4, L=1024, D_MODEL=256, D_INNER=512, D_STATE=16, DT_RANK=16
// Streams: s=0 fwd layer (2*it), s=1 bwd layer (2*it+1), natural time order.
// GEMMs: bf16 MFMA 16x16x32, frag layout [R/16][K/8][16][8]. x,z,xc,y bf16; dt fp32.
// Fusions: LN+in_proj (k_fmm), conv+SiLU+xproj+dtproj (k_xpdt).
// Scan: 3-launch chunked (64 chunks x 16 steps) + parallel wave-shuffle combine (round-7-proven).

#define NCHUNK 64
#define CSTEPS 16

__device__ __forceinline__ float sigmoidf_(float x){ return 1.f/(1.f+__expf(-x)); }
__device__ __forceinline__ short bf16_(float x){
  unsigned u = __float_as_uint(x);
  u += 0x7FFFu + ((u>>16)&1u);
  return (short)(u>>16);
}
__device__ __forceinline__ float f32_(short s){
  return __uint_as_float(((unsigned)(unsigned short)s)<<16);
}

using fragAB = __attribute__((ext_vector_type(8))) short;   // 8 bf16
using fragC  = __attribute__((ext_vector_type(4))) float;   // 4 f32

__global__ __launch_bounds__(256) void k_transpose_in(const float* __restrict__ x, float* __restrict__ hs){
  __shared__ float tile[32][33];
  int b = blockIdx.z;
  int l0 = blockIdx.x*32, c0 = blockIdx.y*32;
  int tx = threadIdx.x, ty = threadIdx.y;
  #pragma unroll
  for (int j=0;j<32;j+=8)
    tile[ty+j][tx] = x[(size_t)b*262144 + (size_t)(c0+ty+j)*1024 + l0 + tx];
  __syncthreads();
  #pragma unroll
  for (int j=0;j<32;j+=8)
    hs[(size_t)b*262144 + (size_t)(l0+ty+j)*256 + (c0+tx)] = tile[tx][ty+j];
}

__global__ __launch_bounds__(256) void k_final(const float* __restrict__ racc, const float* __restrict__ hs, float* __restrict__ out){
  __shared__ float tile[32][33];
  int b = blockIdx.z;
  int l0 = blockIdx.x*32, c0 = blockIdx.y*32;
  int tx = threadIdx.x, ty = threadIdx.y;
  #pragma unroll
  for (int j=0;j<32;j+=8){
    size_t idx = (size_t)b*262144 + (size_t)(l0+ty+j)*256 + c0+tx;
    tile[ty+j][tx] = 2.f*racc[idx] + hs[idx];
  }
  __syncthreads();
  #pragma unroll
  for (int j=0;j<32;j+=8)
    out[(size_t)b*262144 + (size_t)(c0+ty+j)*1024 + l0+tx] = tile[tx][ty+j];
}

// Weights fp32 -> bf16 fragment layout. Flat exact grid.
__global__ __launch_bounds__(256) void k_wconv(
  const float* __restrict__ inw, const float* __restrict__ xpw,
  const float* __restrict__ dtw, const float* __restrict__ otw,
  short* __restrict__ f_inw, short* __restrict__ f_xpw,
  short* __restrict__ f_dtw, short* __restrict__ f_otw)
{
  int b = blockIdx.x, tid = threadIdx.x;
  int which, layer, idx;
  if (b < 4096){ which=0; layer=b>>10; idx=((b&1023)<<8)+tid; }
  else if (b < 4480){ int r=b-4096; which=1; layer=r/96;  idx=(r%96)*256+tid; }
  else if (b < 4736){ int r=b-4480; which=2; layer=r>>6;  idx=(r&63)*256+tid; }
  else              { int r=b-4736; which=3; layer=r>>9;  idx=(r&511)*256+tid; }
  const float* src; short* dst; int R,K,Kp;
  if (which==0){ src=inw; dst=f_inw; R=1024; K=256; Kp=256; }
  else if (which==1){ src=xpw; dst=f_xpw; R=48; K=512; Kp=512; }
  else if (which==2){ src=dtw; dst=f_dtw; R=512; K=16; Kp=32; }
  else { src=otw; dst=f_otw; R=256; K=512; Kp=512; }
  int per = (R>>4)*(Kp>>3)*128;
  int e = idx & 127, tile = idx >> 7;
  int nkt = Kp>>3;
  int kt = tile % nkt, rt = tile / nkt;
  int r = rt*16 + (e>>3), k = kt*8 + (e&7);
  float v = (k<K) ? src[((size_t)layer*R + r)*K + k] : 0.f;
  dst[(size_t)layer*per + idx] = bf16_(v);
}

// Fused LN + in_proj. Block = 128 rows x 128 cols, 4 waves. LN -> LDS frags -> MFMA.
__global__ __launch_bounds__(256) void k_fmm(
  const float* __restrict__ hs, const float* __restrict__ racc_in, float* __restrict__ racc_out,
  const float* __restrict__ nw, const float* __restrict__ nb,
  const short* __restrict__ w_in_base, short* __restrict__ xb, short* __restrict__ zb,
  int layer0, int first)
{
  __shared__ short As[32768];   // 8 rt x 32 kt x 128 = 64KB
  int s = blockIdx.z, bx = blockIdx.x, my = blockIdx.y;
  int layer = layer0 + s;
  int tid = threadIdx.x, lane = tid & 63, w = tid >> 6;
  int m0 = my*128;
  int c0 = lane*4;
  for (int i=0;i<32;++i){
    int lr = w*32 + i;
    size_t idx = (size_t)(m0+lr)*256 + c0;
    float4 rv = *(const float4*)(hs + idx);
    if (!first){
      float4 ra = *(const float4*)(racc_in + idx);
      rv.x += 2.f*ra.x; rv.y += 2.f*ra.y; rv.z += 2.f*ra.z; rv.w += 2.f*ra.w;
    }
    if (bx==0 && s==0) *(float4*)(racc_out + idx) = rv;
    float s1 = rv.x+rv.y+rv.z+rv.w;
    float s2 = rv.x*rv.x+rv.y*rv.y+rv.z*rv.z+rv.w*rv.w;
    #pragma unroll
    for (int o=32;o>=1;o>>=1){ s1+=__shfl_xor(s1,o); s2+=__shfl_xor(s2,o); }
    float mu = s1*(1.f/256.f);
    float var = s2*(1.f/256.f) - mu*mu;
    float inv = rsqrtf(var+1e-5f);
    float4 g = *(const float4*)(nw + (size_t)layer*256 + c0);
    float4 be = *(const float4*)(nb + (size_t)layer*256 + c0);
    int la = ((lr>>4)*32 + (c0>>3))*128 + (lr&15)*8 + (c0&7);
    As[la+0] = bf16_((rv.x-mu)*inv*g.x + be.x);
    As[la+1] = bf16_((rv.y-mu)*inv*g.y + be.y);
    As[la+2] = bf16_((rv.z-mu)*inv*g.z + be.z);
    As[la+3] = bf16_((rv.w-mu)*inv*g.w + be.w);
  }
  __syncthreads();
  int wm = w & 1, wn = w >> 1;
  int mt_base = wm*4;
  int nt_base = bx*8 + wn*4;
  const short* W = w_in_base + (size_t)layer*262144;
  const int loff = lane*8;
  fragC acc[4][4] = {};
  for (int kt=0; kt<32; kt+=4){
    fragAB a[4], bfr[4];
    #pragma unroll
    for (int i=0;i<4;++i)
      a[i] = *(const fragAB*)(As + ((mt_base+i)*32 + kt)*128 + loff);
    #pragma unroll
    for (int j=0;j<4;++j)
      bfr[j] = *(const fragAB*)(W + ((size_t)(nt_base+j)*32 + kt)*128 + loff);
    #pragma unroll
    for (int i=0;i<4;++i)
      #pragma unroll
      for (int j=0;j<4;++j)
        acc[i][j] = __builtin_amdgcn_mfma_f32_16x16x32_bf16(a[i], bfr[j], acc[i][j], 0,0,0);
  }
  int r0 = (lane>>4)*4, cc = lane & 15;
  #pragma unroll
  for (int i=0;i<4;++i){
    int row = m0 + (mt_base+i)*16 + r0;
    #pragma unroll
    for (int j=0;j<4;++j){
      int col = (nt_base+j)*16 + cc;
      #pragma unroll
      for (int r=0;r<4;++r){
        float v = acc[i][j][r];
        int rr = row + r;
        if (col < 512) xb[(size_t)s*2097152 + (size_t)rr*512 + col] = bf16_(v);
        else           zb[(size_t)s*2097152 + (size_t)rr*512 + (col-512)] = bf16_(v);
      }
    }
  }
}

// Fused conv(+SiLU) + xproj + dtproj. Block = 32 rows.
__global__ __launch_bounds__(256) void k_xpdt(
  const short* __restrict__ xb, short* __restrict__ xc_f,
  const float* __restrict__ cw, const float* __restrict__ cb,
  const short* __restrict__ wxp, const short* __restrict__ wdt, const float* __restrict__ dtb,
  float* __restrict__ dbl, float* __restrict__ dtv, int layer0)
{
  __shared__ short xcs[16384];     // 2 rt x 64 kt x 128 = 32KB
  __shared__ short dt_lds[32][24];
  int z = blockIdx.y, by = blockIdx.x;
  int layer = layer0 + z;
  int tid = threadIdx.x, lane = tid & 63, wn = tid >> 6;
  int b = by >> 5, l0 = (by & 31) << 5;
  {
    int d0 = tid*2;
    const short* xs = xb + (size_t)z*2097152 + (size_t)b*524288;
    float wt[2][4], bias2[2];
    #pragma unroll
    for (int q=0;q<2;++q){
      float4 wv = *(const float4*)(cw + ((size_t)layer*512 + d0 + q)*4);
      wt[q][0]=wv.x; wt[q][1]=wv.y; wt[q][2]=wv.z; wt[q][3]=wv.w;
      bias2[q] = cb[(size_t)layer*512 + d0 + q];
    }
    float xm[3][2];
    short* xg = xc_f + (size_t)z*2097152;
    #pragma unroll
    for (int q=0;q<3;++q){
      int l = z==0 ? (l0-3+q) : (l0+34-q);
      if (l<0 || l>1023){ xm[q][0]=0.f; xm[q][1]=0.f; }
      else { unsigned u = *(const unsigned*)(xs + (size_t)l*512 + d0);
             xm[q][0]=f32_((short)(u&0xFFFF)); xm[q][1]=f32_((short)(u>>16)); }
    }
    for (int step=0; step<32; ++step){
      int i = z==0 ? step : (31-step);
      int l = l0 + i;
      unsigned u = *(const unsigned*)(xs + (size_t)l*512 + d0);
      float xt0 = f32_((short)(u&0xFFFF)), xt1 = f32_((short)(u>>16));
      float a0 = bias2[0] + wt[0][0]*xm[0][0] + wt[0][1]*xm[1][0] + wt[0][2]*xm[2][0] + wt[0][3]*xt0;
      float a1 = bias2[1] + wt[1][0]*xm[0][1] + wt[1][1]*xm[1][1] + wt[1][2]*xm[2][1] + wt[1][3]*xt1;
      float v0 = a0*sigmoidf_(a0), v1 = a1*sigmoidf_(a1);
      unsigned pv = (unsigned)(unsigned short)bf16_(v0) | ((unsigned)(unsigned short)bf16_(v1)<<16);
      int la = ((i>>4)*64 + (d0>>3))*128 + (i&15)*8 + (d0&7);
      *(unsigned*)(xcs + la) = pv;
      int grow = b*1024 + l;
      *(unsigned*)(xg + (((size_t)(grow>>4)*64 + (size_t)(d0>>3))*128 + (size_t)(grow&15)*8 + (d0&7))) = pv;
      xm[0][0]=xm[1][0]; xm[0][1]=xm[1][1];
      xm[1][0]=xm[2][0]; xm[1][1]=xm[2][1];
      xm[2][0]=xt0;      xm[2][1]=xt1;
    }
  }
  __syncthreads();
  const int loff = lane*8;
  int r0 = (lane>>4)*4, cc = lane & 15;
  {
    fragC acc[2] = {};
    int nt = wn < 3 ? wn : 2;
    const short* Wx = wxp + (size_t)layer*24576;
    for (int kt=0; kt<64; kt+=4){
      fragAB a0 = *(const fragAB*)(xcs + (0*64 + kt)*128 + loff);
      fragAB a1 = *(const fragAB*)(xcs + (1*64 + kt)*128 + loff);
      fragAB bb = *(const fragAB*)(Wx + ((size_t)nt*64 + kt)*128 + loff);
      acc[0] = __builtin_amdgcn_mfma_f32_16x16x32_bf16(a0, bb, acc[0], 0,0,0);
      acc[1] = __builtin_amdgcn_mfma_f32_16x16x32_bf16(a1, bb, acc[1], 0,0,0);
    }
    int col = nt*16 + cc;
    #pragma unroll
    for (int i=0;i<2;++i){
      int lr = i*16 + r0;
      int grow = by*32 + lr;
      #pragma unroll
      for (int r=0;r<4;++r){
        float v = acc[i][r];
        if (wn==1 || wn==2)
          dbl[(size_t)z*196608 + (size_t)(grow+r)*48 + col] = v;
        if (wn==0)
          dt_lds[lr+r][cc] = bf16_(v);
      }
    }
  }
  __syncthreads();
  {
    float* dto = dtv + (size_t)z*2097152;
    const float* bias = dtb + (size_t)layer*512;
    const short* WD = wdt + (size_t)layer*16384;
    int kq = lane >> 4;
    fragAB a2[2];
    #pragma unroll
    for (int i=0;i<2;++i){
      fragAB t = {};
      if (kq < 2){
        #pragma unroll
        for (int j=0;j<8;++j) t[j] = dt_lds[i*16 + (lane&15)][kq*8 + j];
      }
      a2[i] = t;
    }
    #pragma unroll
    for (int c2=0;c2<2;++c2){
      fragC acc2[2][4] = {};
      fragAB b2[4];
      #pragma unroll
      for (int j=0;j<4;++j){
        int ntj = wn*8 + c2*4 + j;
        b2[j] = *(const fragAB*)(WD + ((size_t)ntj*4)*128 + loff);
      }
      #pragma unroll
      for (int i=0;i<2;++i)
        #pragma unroll
        for (int j=0;j<4;++j)
          acc2[i][j] = __builtin_amdgcn_mfma_f32_16x16x32_bf16(a2[i], b2[j], acc2[i][j], 0,0,0);
      #pragma unroll
      for (int i=0;i<2;++i){
        int grow = by*32 + i*16 + r0;
        #pragma unroll
        for (int j=0;j<4;++j){
          int col2 = (wn*8 + c2*4 + j)*16 + cc;
          #pragma unroll
          for (int r=0;r<4;++r){
            float v = acc2[i][j][r] + bias[col2];
            v = (v > 20.f) ? v : log1pf(__expf(v));
            dto[(size_t)(grow+r)*512 + col2] = v;
          }
        }
      }
    }
  }
}

__device__ __forceinline__ float ld_xc(const short* xcf, int row, int d){
  return f32_(xcf[(((size_t)(row>>4)*64 + (d>>3))*16 + (row&15))*8 + (d&7)]);
}

__global__ __launch_bounds__(256) void k_scan_a(
  const float* __restrict__ dtv, const short* __restrict__ xc_f,
  const float* __restrict__ dbl, const float* __restrict__ A_log,
  float* __restrict__ dtsum, float* __restrict__ hF, int layer0)
{
  int d = blockIdx.x*256 + threadIdx.x;
  int k = blockIdx.y;
  int sb = blockIdx.z;
  int s = sb >> 2, b = sb & 3;
  int layer = layer0 + s;
  float Av[16];
  #pragma unroll
  for (int n=0;n<16;++n) Av[n] = -__expf(A_log[((size_t)layer*512 + d)*16 + n]);
  const float* dt_p = dtv + (size_t)sb*524288 + d;
  const short* xcf = xc_f + (size_t)s*2097152;
  const float* bc_p = dbl + (size_t)sb*49152;
  float h[16];
  #pragma unroll
  for (int n=0;n<16;++n) h[n] = 0.f;
  float ssum = 0.f;
  int u0 = k*CSTEPS;
  #pragma unroll
  for (int i=0;i<CSTEPS;++i){
    int u = u0 + i;
    int t = s ? (1023 - u) : u;
    int row = b*1024 + t;
    float dtval = dt_p[(size_t)t*512];
    float xv = ld_xc(xcf, row, d);
    const float4* bp = (const float4*)(bc_p + (size_t)t*48 + 16);
    float4 B0 = bp[0], B1 = bp[1], B2 = bp[2], B3 = bp[3];
    float Bv[16] = {B0.x,B0.y,B0.z,B0.w,B1.x,B1.y,B1.z,B1.w,
                    B2.x,B2.y,B2.z,B2.w,B3.x,B3.y,B3.z,B3.w};
    float w = dtval * xv;
    ssum += dtval;
    #pragma unroll
    for (int n=0;n<16;++n)
      h[n] = fmaf(__expf(dtval*Av[n]), h[n], w*Bv[n]);
  }
  size_t base = (size_t)(sb*NCHUNK + k)*512 + d;
  dtsum[base] = ssum;
  float4* hp = (float4*)(hF + base*16);
  #pragma unroll
  for (int q=0;q<4;++q) hp[q] = make_float4(h[4*q],h[4*q+1],h[4*q+2],h[4*q+3]);
}

// Parallel combine: block = (d, sb); wave-shuffle exclusive scan over 64 chunk states, in place.
__global__ __launch_bounds__(256) void k_scan_c(
  const float* __restrict__ dtsum, float* __restrict__ hF,
  const float* __restrict__ A_log, int layer0)
{
  __shared__ float tile[64][17];
  __shared__ float ds[64];
  int d = blockIdx.x, sb = blockIdx.y;
  int tid = threadIdx.x, lane = tid & 63, w = tid >> 6;
  int layer = layer0 + (sb >> 2);
  size_t base = (size_t)sb*64*8192 + (size_t)d*16;    // + k*8192 + n
  {
    int k = tid >> 2, n0 = (tid & 3)*4;
    float4 v = *(const float4*)(hF + base + (size_t)k*8192 + n0);
    tile[k][n0+0]=v.x; tile[k][n0+1]=v.y; tile[k][n0+2]=v.z; tile[k][n0+3]=v.w;
  }
  if (tid < 64) ds[tid] = dtsum[((size_t)sb*64 + tid)*512 + d];
  __syncthreads();
  float dsk = ds[lane];
  #pragma unroll
  for (int p=0;p<4;++p){
    int n = p*4 + w;
    float Av = -__expf(A_log[((size_t)layer*512 + d)*16 + n]);
    float a = __expf(Av * dsk);
    float h = tile[lane][n];
    #pragma unroll
    for (int o=1;o<64;o<<=1){
      float au = __shfl_up(a, o);
      float hu = __shfl_up(h, o);
      if (lane >= o){ h = fmaf(a, hu, h); a *= au; }
    }
    float h0 = __shfl_up(h, 1);
    if (lane == 0) h0 = 0.f;
    tile[lane][n] = h0;
  }
  __syncthreads();
  {
    int k = tid >> 2, n0 = (tid & 3)*4;
    float4 v = make_float4(tile[k][n0], tile[k][n0+1], tile[k][n0+2], tile[k][n0+3]);
    *(float4*)(hF + base + (size_t)k*8192 + n0) = v;
  }
}

// Pass B: recompute within chunk from h0 (in hF), emit gated y as bf16 fragments.
__global__ __launch_bounds__(256) void k_scan_b(
  const float* __restrict__ dtv, const short* __restrict__ xc_f, const short* __restrict__ zb,
  const float* __restrict__ dbl, const float* __restrict__ A_log, const float* __restrict__ Dp,
  const float* __restrict__ h0p, short* __restrict__ y_f, int layer0)
{
  int d = blockIdx.x*256 + threadIdx.x;
  int k = blockIdx.y;
  int sb = blockIdx.z;
  int s = sb >> 2, b = sb & 3;
  int layer = layer0 + s;
  float Av[16];
  #pragma unroll
  for (int n=0;n<16;++n) Av[n] = -__expf(A_log[((size_t)layer*512 + d)*16 + n]);
  float Dv = Dp[(size_t)layer*512 + d];
  const float* dt_p = dtv + (size_t)sb*524288 + d;
  const short* xcf = xc_f + (size_t)s*2097152;
  const short* z_p = zb + (size_t)s*2097152 + (size_t)b*524288 + d;
  const float* bc_p = dbl + (size_t)sb*49152;
  size_t base = (size_t)(sb*NCHUNK + k)*512 + d;
  float h[16];
  const float4* hp = (const float4*)(h0p + base*16);
  #pragma unroll
  for (int q=0;q<4;++q){
    float4 v = hp[q];
    h[4*q]=v.x; h[4*q+1]=v.y; h[4*q+2]=v.z; h[4*q+3]=v.w;
  }
  short* yo = y_f + (size_t)s*2097152;
  int u0 = k*CSTEPS;
  #pragma unroll
  for (int i=0;i<CSTEPS;++i){
    int u = u0 + i;
    int t = s ? (1023 - u) : u;
    int row = b*1024 + t;
    float dtval = dt_p[(size_t)t*512];
    float xv = ld_xc(xcf, row, d);
    const float4* bp = (const float4*)(bc_p + (size_t)t*48 + 16);
    float4 B0 = bp[0], B1 = bp[1], B2 = bp[2], B3 = bp[3];
    float4 C0 = bp[4], C1 = bp[5], C2 = bp[6], C3 = bp[7];
    float Bv[16] = {B0.x,B0.y,B0.z,B0.w,B1.x,B1.y,B1.z,B1.w,
                    B2.x,B2.y,B2.z,B2.w,B3.x,B3.y,B3.z,B3.w};
    float Cv[16] = {C0.x,C0.y,C0.z,C0.w,C1.x,C1.y,C1.z,C1.w,
                    C2.x,C2.y,C2.z,C2.w,C3.x,C3.y,C3.z,C3.w};
    float w = dtval * xv;
    float y = 0.f;
    #pragma unroll
    for (int n=0;n<16;++n){
      h[n] = fmaf(__expf(dtval*Av[n]), h[n], w*Bv[n]);
      y = fmaf(h[n], Cv[n], y);
    }
    float zv = f32_(z_p[(size_t)t*512]);
    float yv = (y + Dv*xv) * (zv*sigmoidf_(zv));
    yo[(((size_t)(row>>4)*64 + (d>>3))*16 + (row&15))*8 + (d&7)] = bf16_(yv);
  }
}

// out_proj dual-stream GEMM, 64x64 block (256 blocks = full CU coverage), 4 waves 32x32 each.
__global__ __launch_bounds__(256) void k_mmo(
  const short* __restrict__ Af, const short* __restrict__ Wf,
  const short* __restrict__ A2f, const short* __restrict__ W2f,
  float* __restrict__ C)
{
  int tid = threadIdx.x;
  int lane = tid & 63, wid = tid >> 6;
  int wm = wid & 1, wn = wid >> 1;
  int mt_base = blockIdx.y*4 + wm*2;
  int nt_base = blockIdx.x*4 + wn*2;
  const int K8 = 64;
  const int loff = lane*8;
  fragC acc[2][2] = {};
  const short* Aps[2] = { Af, A2f };
  const short* Wps[2] = { Wf, W2f };
  for (int sgi=0; sgi<2; ++sgi){
    const short* A = Aps[sgi];
    const short* W = Wps[sgi];
    for (int kt=0; kt<K8; kt+=4){
      fragAB a[2], bfr[2];
      #pragma unroll
      for (int i=0;i<2;++i)
        a[i] = *(const fragAB*)(A + ((size_t)(mt_base+i)*K8 + kt)*128 + loff);
      #pragma unroll
      for (int j=0;j<2;++j)
        bfr[j] = *(const fragAB*)(W + ((size_t)(nt_base+j)*K8 + kt)*128 + loff);
      #pragma unroll
      for (int i=0;i<2;++i)
        #pragma unroll
        for (int j=0;j<2;++j)
          acc[i][j] = __builtin_amdgcn_mfma_f32_16x16x32_bf16(a[i], bfr[j], acc[i][j], 0,0,0);
    }
  }
  int r0 = (lane>>4)*4, cc = lane & 15;
  #pragma unroll
  for (int i=0;i<2;++i){
    int row = (mt_base+i)*16 + r0;
    #pragma unroll
    for (int j=0;j<2;++j){
      int col = (nt_base+j)*16 + cc;
      #pragma unroll
      for (int r=0;r<4;++r)
        C[(size_t)(row+r)*256 + col] = acc[i][j][r];
    }
  }
}

extern "C" void kernel_launch(void* const* d_in, const int* in_sizes, int n_in,
                              void* d_out, int out_size, void* d_ws, size_t ws_size,
                              hipStream_t stream) {
  const float* x        = (const float*)d_in[0];
  const float* norm_w   = (const float*)d_in[1];
  const float* norm_b   = (const float*)d_in[2];
  const float* in_w     = (const float*)d_in[3];
  const float* conv_w   = (const float*)d_in[4];
  const float* conv_b   = (const float*)d_in[5];
  const float* xproj_w  = (const float*)d_in[6];
  const float* dtproj_w = (const float*)d_in[7];
  const float* dtproj_b = (const float*)d_in[8];
  const float* A_log    = (const float*)d_in[9];
  const float* Dp       = (const float*)d_in[10];
  const float* out_w    = (const float*)d_in[11];
  float* out = (float*)d_out;
  float* ws = (float*)d_ws;

  float* hs    = ws;                        // 1048576 f
  float* raccA = ws + 1048576;              // 1048576 f
  float* raccB = ws + 2097152;              // 1048576 f
  short* xb    = (short*)(ws + 3145728);    // 2x2097152 bf16
  short* zb    = (short*)(ws + 5242880);    // 2x2097152 bf16
  short* xc_f  = (short*)(ws + 7340032);    // 2x2097152 bf16 (frag)
  short* y_f   = (short*)(ws + 9437184);    // 2x2097152 bf16 (frag)
  float* dbl   = ws + 11534336;             // 393216 f
  float* dtv   = ws + 11927552;             // 4194304 f
  float* dtsum = ws + 16121856;             // 262144 f (8x64x512)
  float* hF    = ws + 16384000;             // 4194304 f (8x64x512x16)
  short* w_inw = (short*)(ws + 20578304);   // 4x262144 bf16
  short* w_xp  = w_inw + 1048576;           // 4x24576
  short* w_dt  = w_xp + 98304;              // 4x16384
  short* w_out = w_dt + 65536;              // 4x131072

  k_wconv<<<6784, 256, 0, stream>>>(in_w, xproj_w, dtproj_w, out_w, w_inw, w_xp, w_dt, w_out);
  k_transpose_in<<<dim3(32,8,4), dim3(32,8), 0, stream>>>(x, hs);

  for (int it=0; it<2; ++it){
    int layer0 = 2*it;
    k_fmm<<<dim3(8,32,2), 256, 0, stream>>>(hs, it ? raccA : nullptr, it ? raccB : raccA,
        norm_w, norm_b, w_inw, xb, zb, layer0, it==0 ? 1 : 0);
    k_xpdt<<<dim3(128,2), 256, 0, stream>>>(xb, xc_f, conv_w, conv_b,
        w_xp, w_dt, dtproj_b, dbl, dtv, layer0);
    k_scan_a<<<dim3(2,NCHUNK,8), 256, 0, stream>>>(dtv, xc_f, dbl, A_log, dtsum, hF, layer0);
    k_scan_c<<<dim3(512,8), 256, 0, stream>>>(dtsum, hF, A_log, layer0);
    k_scan_b<<<dim3(2,NCHUNK,8), 256, 0, stream>>>(dtv, xc_f, zb, dbl, A_log, Dp, hF, y_f, layer0);
    k_mmo<<<dim3(4,64), 256, 0, stream>>>(y_f, w_out + (size_t)layer0*131072,
        y_f + 2097152, w_out + (size_t)(layer0+1)*131072, hs);
  }
  k_final<<<dim3(32,8,4), dim3(32,8), 0, stream>>>(raccB, hs, out);
}